// Round 14
// baseline (550.211 us; speedup 1.0000x reference)
//
#include <hip/hip_runtime.h>

#define L2E 1.4426950408889634f

typedef short bf16x8 __attribute__((ext_vector_type(8)));
typedef short short4v __attribute__((ext_vector_type(4)));
typedef float f32x4 __attribute__((ext_vector_type(4)));

__device__ __forceinline__ short bf16hi(float x) {
    return (short)(__builtin_bit_cast(unsigned int, x) >> 16);
}
__device__ __forceinline__ float bf16tof(short h) {
    return __builtin_bit_cast(float, ((unsigned int)(unsigned short)h) << 16);
}

// ---------------- Wsum ----------------
__global__ __launch_bounds__(256) void wsum_kernel(const float* __restrict__ W,
                                                   float* __restrict__ wsum) {
    int wave = threadIdx.x >> 6, lane = threadIdx.x & 63;
    int h = blockIdx.x * 4 + wave;
    const float* row = W + (size_t)h * 1024;
    float s = 0.f;
#pragma unroll
    for (int i = 0; i < 16; ++i) s += row[lane + 64 * i];
#pragma unroll
    for (int off = 32; off; off >>= 1) s += __shfl_xor(s, off, 64);
    if (lane == 0) wsum[h] = s;
}

// ------- prep: pair-major zero-diag transposed tables (R13) -----------------
__global__ __launch_bounds__(256) void prep_kernel(const float* __restrict__ cov,
                                                   const float* __restrict__ ld,
                                                   float2* __restrict__ covP,
                                                   float4* __restrict__ clP) {
    __shared__ float tc[32][33];
    __shared__ float tl[32][33];
    const int bx = blockIdx.x * 32, by = blockIdx.y * 32;
    const int x = threadIdx.x & 31;
    const int y = threadIdx.x >> 5;
#pragma unroll
    for (int i = 0; i < 32; i += 8) {
        int r = by + y + i, c = bx + x;
        float cv = cov[(size_t)r * 256 + c];
        float lv = ld[(size_t)r * 256 + c];
        if (r == c) { cv = 0.f; lv = 0.f; }
        tc[y + i][x] = cv; tl[y + i][x] = lv;
    }
    __syncthreads();
    const int k = by + x;
#pragma unroll
    for (int i2 = 0; i2 < 16; i2 += 8) {
        int y2 = y + i2;
        int jp = (bx >> 1) + y2;
        float c0 = tc[x][2 * y2],     l0 = tl[x][2 * y2];
        float c1 = tc[x][2 * y2 + 1], l1 = tl[x][2 * y2 + 1];
        covP[(size_t)jp * 256 + k] = make_float2(c0, c1);
        clP[(size_t)jp * 256 + k]  = make_float4(c0, l0, c1, l1);
    }
}

// ---------------- GEMM fp32 (R5, proven) ------------------------------------
#define BK 16
#define LDT 68

__global__ __launch_bounds__(256) void gemm_kernel(const float* __restrict__ X,
                                                   const float* __restrict__ W,
                                                   float* __restrict__ C) {
    __shared__ float As[BK][LDT];
    __shared__ float Bs[BK][LDT];
    const int tid = threadIdx.x;
    const int row = tid >> 2;
    const int c4  = (tid & 3) << 2;
    const int gm0 = blockIdx.x * 64;
    const int gn0 = blockIdx.y * 64;
    const int tx = tid & 15, ty = tid >> 4;
    float acc[4][4] = {};
    const float* Xp = X + (size_t)(gm0 + row) * 1024 + c4;
    const float* Wp = W + (size_t)(gn0 + row) * 1024 + c4;

    float4 a = *(const float4*)(Xp);
    float4 b = *(const float4*)(Wp);
    for (int kt = 0; kt < 1024; kt += BK) {
        __syncthreads();
        As[c4 + 0][row] = a.x; As[c4 + 1][row] = a.y;
        As[c4 + 2][row] = a.z; As[c4 + 3][row] = a.w;
        Bs[c4 + 0][row] = b.x; Bs[c4 + 1][row] = b.y;
        Bs[c4 + 2][row] = b.z; Bs[c4 + 3][row] = b.w;
        __syncthreads();
        if (kt + BK < 1024) {
            a = *(const float4*)(Xp + kt + BK);
            b = *(const float4*)(Wp + kt + BK);
        }
#pragma unroll
        for (int kk = 0; kk < BK; ++kk) {
            float4 av = *(const float4*)&As[kk][ty << 2];
            float4 bv = *(const float4*)&Bs[kk][tx << 2];
            float am[4] = {av.x, av.y, av.z, av.w};
            float bn[4] = {bv.x, bv.y, bv.z, bv.w};
#pragma unroll
            for (int i = 0; i < 4; ++i)
#pragma unroll
                for (int j = 0; j < 4; ++j)
                    acc[i][j] = __builtin_fmaf(am[i], bn[j], acc[i][j]);
        }
    }
#pragma unroll
    for (int i = 0; i < 4; ++i) {
        float4 o = {acc[i][0], acc[i][1], acc[i][2], acc[i][3]};
        *(float4*)(C + (size_t)(gm0 + (ty << 2) + i) * 256 + gn0 + (tx << 2)) = o;
    }
}

// ------- prep_w variants: W -> hi/lo bf16 fragment tables -------------------
// blocked map: lane l elem i <-> k = 32s + 16*(i>>2) + 4*(l>>4) + (i&3)
__global__ __launch_bounds__(256) void prep_w_blk(const float* __restrict__ W,
                                                  short* __restrict__ WhT,
                                                  short* __restrict__ WlT) {
    int id = blockIdx.x * 256 + threadIdx.x;
    int rem = id & 1023;
    int s = id >> 10, c = rem >> 6, l = rem & 63;
    int n = 16 * c + (l & 15);
    int k0 = 32 * s + 4 * (l >> 4);
    const float* p = W + (size_t)n * 1024 + k0;
    short h[8], lo[8];
#pragma unroll
    for (int i = 0; i < 8; ++i) {
        float v = p[(i & 3) + 16 * (i >> 2)];
        short hh = bf16hi(v);
        h[i] = hh; lo[i] = bf16hi(v - bf16tof(hh));
    }
    *(bf16x8*)(WhT + (size_t)id * 8) = *(bf16x8*)h;
    *(bf16x8*)(WlT + (size_t)id * 8) = *(bf16x8*)lo;
}
// linear map: lane l elem i <-> k = 32s + 8*(l>>4) + i
__global__ __launch_bounds__(256) void prep_w_lin(const float* __restrict__ W,
                                                  short* __restrict__ WhT,
                                                  short* __restrict__ WlT) {
    int id = blockIdx.x * 256 + threadIdx.x;
    int rem = id & 1023;
    int s = id >> 10, c = rem >> 6, l = rem & 63;
    int n = 16 * c + (l & 15);
    int k0 = 32 * s + 8 * (l >> 4);
    const float* p = W + (size_t)n * 1024 + k0;
    short h[8], lo[8];
#pragma unroll
    for (int i = 0; i < 8; ++i) {
        float v = p[i];
        short hh = bf16hi(v);
        h[i] = hh; lo[i] = bf16hi(v - bf16tof(hh));
    }
    *(bf16x8*)(WhT + (size_t)id * 8) = *(bf16x8*)h;
    *(bf16x8*)(WlT + (size_t)id * 8) = *(bf16x8*)lo;
}

// ------- MFMA diagnostic GEMM: rows [0,2048) only, writes Cm ----------------
// AMAP: 0 blocked, 1 linear (X staging).  DSWAP: 0 normal (row=4*(l>>4)+r,
// col=l&15), 1 transposed.
template<int AMAP, int DSWAP>
__global__ __launch_bounds__(512) void mfma_gemm(const float* __restrict__ X,
                                                 const short* __restrict__ WhT,
                                                 const short* __restrict__ WlT,
                                                 float* __restrict__ Cm) {
    __shared__ short Ah[2][64][8];
    __shared__ short Al[2][64][8];
    __shared__ short Wh[16][64][8];
    __shared__ short Wl[16][64][8];
    const int tid = threadIdx.x;
    const int l = tid & 63, w = tid >> 6;
    const int gm0 = blockIdx.x * 32;

    const int xr = tid >> 3, xg = tid & 7;
    const float* Xp = X + (size_t)(gm0 + xr) * 1024 + 4 * xg;

    float4 xv;
    bf16x8 wh0, wh1, wl0, wl1;
    if (tid < 256) xv = *(const float4*)(Xp);
    wh0 = *(const bf16x8*)(WhT + (size_t)tid * 8);
    wh1 = *(const bf16x8*)(WhT + (size_t)(tid + 512) * 8);
    wl0 = *(const bf16x8*)(WlT + (size_t)tid * 8);
    wl1 = *(const bf16x8*)(WlT + (size_t)(tid + 512) * 8);

    const int rt = w & 1, cg = w >> 1;
    f32x4 acc[4] = {};

    for (int s = 0; s < 32; ++s) {
        __syncthreads();
        if (tid < 256) {
            float vv[4] = {xv.x, xv.y, xv.z, xv.w};
            short h[4], lo[4];
#pragma unroll
            for (int i = 0; i < 4; ++i) {
                short hh = bf16hi(vv[i]);
                h[i] = hh; lo[i] = bf16hi(vv[i] - bf16tof(hh));
            }
            int lane, e0;
            if (AMAP == 0) { lane = (xr & 15) + 16 * (xg & 3); e0 = (xg >> 2) * 4; }
            else           { lane = (xr & 15) + 16 * (xg >> 1); e0 = (xg & 1) * 4; }
            *(short4v*)&Ah[xr >> 4][lane][e0] = *(short4v*)h;
            *(short4v*)&Al[xr >> 4][lane][e0] = *(short4v*)lo;
        }
        ((bf16x8*)Wh)[tid]       = wh0;
        ((bf16x8*)Wh)[tid + 512] = wh1;
        ((bf16x8*)Wl)[tid]       = wl0;
        ((bf16x8*)Wl)[tid + 512] = wl1;
        __syncthreads();
        if (s < 31) {
            if (tid < 256) xv = *(const float4*)(Xp + (s + 1) * 32);
            const size_t wo = (size_t)(s + 1) * 8192;
            wh0 = *(const bf16x8*)(WhT + wo + (size_t)tid * 8);
            wh1 = *(const bf16x8*)(WhT + wo + (size_t)(tid + 512) * 8);
            wl0 = *(const bf16x8*)(WlT + wo + (size_t)tid * 8);
            wl1 = *(const bf16x8*)(WlT + wo + (size_t)(tid + 512) * 8);
        }
        bf16x8 ah = *(bf16x8*)&Ah[rt][l][0];
        bf16x8 al = *(bf16x8*)&Al[rt][l][0];
#pragma unroll
        for (int cc = 0; cc < 4; ++cc) {
            int c = cg * 4 + cc;
            bf16x8 bh = *(bf16x8*)&Wh[c][l][0];
            bf16x8 bl = *(bf16x8*)&Wl[c][l][0];
            acc[cc] = __builtin_amdgcn_mfma_f32_16x16x32_bf16(ah, bh, acc[cc], 0, 0, 0);
            acc[cc] = __builtin_amdgcn_mfma_f32_16x16x32_bf16(ah, bl, acc[cc], 0, 0, 0);
            acc[cc] = __builtin_amdgcn_mfma_f32_16x16x32_bf16(al, bh, acc[cc], 0, 0, 0);
        }
    }
#pragma unroll
    for (int cc = 0; cc < 4; ++cc) {
        int c = cg * 4 + cc;
#pragma unroll
        for (int r = 0; r < 4; ++r) {
            if (DSWAP == 0) {
                int rowg = gm0 + rt * 16 + 4 * (l >> 4) + r;
                Cm[(size_t)rowg * 256 + c * 16 + (l & 15)] = acc[cc][r];
            } else {
                int rowg = gm0 + rt * 16 + (l & 15);
                Cm[(size_t)rowg * 256 + c * 16 + 4 * (l >> 4) + r] = acc[cc][r];
            }
        }
    }
}

// ------- verify kernels: spin (distinct lengths) iff mismatch ---------------
__device__ __forceinline__ void verify_body(const float* __restrict__ Cref,
                                            const float* __restrict__ Cm,
                                            int spin) {
    int idx = (blockIdx.x * 256 + threadIdx.x) * 4;
    float4 a = *(const float4*)(Cref + idx);
    float4 b = *(const float4*)(Cm + idx);
    bool bad = fabsf(a.x - b.x) > 0.2f || fabsf(a.y - b.y) > 0.2f ||
               fabsf(a.z - b.z) > 0.2f || fabsf(a.w - b.w) > 0.2f;
    if (__any(bad)) {
        float x = (float)threadIdx.x;
        for (int i = 0; i < spin; ++i) x = __builtin_fmaf(x, 1.0000001f, 1e-9f);
        asm volatile("" :: "v"(x));
    }
}
__global__ __launch_bounds__(256) void verify0(const float* a, const float* b) { verify_body(a, b, 20000); }
__global__ __launch_bounds__(256) void verify1(const float* a, const float* b) { verify_body(a, b, 35000); }
__global__ __launch_bounds__(256) void verify2(const float* a, const float* b) { verify_body(a, b, 50000); }
__global__ __launch_bounds__(256) void verify3(const float* a, const float* b) { verify_body(a, b, 65000); }

// ---------------- Head (R13, proven) ----------------------------------------
#define NB 4

__global__ __launch_bounds__(256) void head_kernel(const float* __restrict__ C,
                                                   const float* __restrict__ wsum,
                                                   const float2* __restrict__ covP,
                                                   const float4* __restrict__ clP,
                                                   const float* __restrict__ cov,
                                                   const float* __restrict__ ld,
                                                   float* __restrict__ out) {
    __shared__ float4 omI[256];
    __shared__ float4 vaI[256];
    const int k = threadIdx.x;
    const int b0 = blockIdx.x * NB;

    const float ws = wsum[k];
    const float cdiag = cov[(size_t)k * 257];
    const float ldiag = ld[(size_t)k * 257];

    float mk[NB], vak[NB], omk[NB], sp[NB], pmax[NB], pmin[NB];
#pragma unroll
    for (int b = 0; b < NB; ++b) {
        float va = C[(size_t)(2 * (b0 + b)) * 256 + k];
        float ms = C[(size_t)(2 * (b0 + b) + 1) * 256 + k];
        float o  = ws - ms;
        mk[b] = ms; vak[b] = va; omk[b] = o;
        ((float*)&omI[k])[b] = o;
        ((float*)&vaI[k])[b] = va;
        sp[b] = 0.f; pmax[b] = 0.f; pmin[b] = 0.f;
    }
    __syncthreads();

    const float2* cp = covP + k;
#pragma unroll 4
    for (int jp = 0; jp < 128; ++jp) {
        float2 cv = cp[(size_t)jp * 256];
        float4 om0 = omI[2 * jp];
        float4 om1 = omI[2 * jp + 1];
        float o0[4] = {om0.x, om0.y, om0.z, om0.w};
        float o1[4] = {om1.x, om1.y, om1.z, om1.w};
#pragma unroll
        for (int b = 0; b < NB; ++b) {
            float p0 = cv.x * o0[b];
            float p1 = cv.y * o1[b];
            sp[b]  += p0 + p1;
            pmax[b] = fmaxf(fmaxf(pmax[b], p0), p1);
            pmin[b] = fminf(fminf(pmin[b], p0), p1);
        }
    }

    float c1[NB], c0[NB], ek[NB], se[NB], dp[NB];
#pragma unroll
    for (int b = 0; b < NB; ++b) {
        float m   = mk[b];
        float pkk = cdiag * omk[b];
        float rkk = __builtin_fmaf(m, pkk, 1.0f);
        float sum = __builtin_fmaf(m, sp[b] + pkk, 1.0f);
        float iv  = __builtin_amdgcn_rcpf(sum);
        float rmax = (m >= 0.f) ? m * pmax[b] : m * pmin[b];
        float rmin = (m >= 0.f) ? m * pmin[b] : m * pmax[b];
        rmax = fmaxf(rmax, rkk);
        rmin = fminf(rmin, rkk);
        float mx = (iv >= 0.f) ? iv * rmax : iv * rmin;
        c1[b] = m * iv * L2E;
        c0[b] = -mx * L2E;
        ek[b] = __builtin_amdgcn_exp2f(__builtin_fmaf(rkk * iv, L2E, c0[b]));
        se[b] = 0.f; dp[b] = 0.f;
    }

    const float4* lp = clP + k;
#pragma unroll 4
    for (int jp = 0; jp < 128; ++jp) {
        float4 cl = lp[(size_t)jp * 256];
        float4 om0 = omI[2 * jp];
        float4 om1 = omI[2 * jp + 1];
        float4 va0 = vaI[2 * jp];
        float4 va1 = vaI[2 * jp + 1];
        float o0[4] = {om0.x, om0.y, om0.z, om0.w};
        float o1[4] = {om1.x, om1.y, om1.z, om1.w};
        float v0[4] = {va0.x, va0.y, va0.z, va0.w};
        float v1[4] = {va1.x, va1.y, va1.z, va1.w};
#pragma unroll
        for (int b = 0; b < NB; ++b) {
            float p0 = cl.x * o0[b];
            float e0 = __builtin_amdgcn_exp2f(__builtin_fmaf(p0, c1[b], c0[b]));
            float p1 = cl.z * o1[b];
            float e1 = __builtin_amdgcn_exp2f(__builtin_fmaf(p1, c1[b], c0[b]));
            se[b] += e0 + e1;
            dp[b]  = __builtin_fmaf(e0, cl.y * v0[b], dp[b]);
            dp[b]  = __builtin_fmaf(e1, cl.w * v1[b], dp[b]);
        }
    }

#pragma unroll
    for (int b = 0; b < NB; ++b) {
        float espur = __builtin_amdgcn_exp2f(c0[b]);
        float sef = se[b] + (ek[b] - espur);
        float dpf = __builtin_fmaf(ek[b], ldiag * vak[b], dp[b]);
        out[(size_t)(b0 + b) * 256 + k] = dpf * __builtin_amdgcn_rcpf(sef);
    }
}

extern "C" void kernel_launch(void* const* d_in, const int* in_sizes, int n_in,
                              void* d_out, int out_size, void* d_ws, size_t ws_size,
                              hipStream_t stream) {
    const float* x    = (const float*)d_in[0];
    const float* W    = (const float*)d_in[1];
    const float* cov  = (const float*)d_in[2];
    const float* ldng = (const float*)d_in[3];
    float* out = (float*)d_out;

    // ws: R13-proven footprint
    float*  C    = (float*)d_ws;                         // [8192,256]
    float*  wsum = C + (size_t)8192 * 256;
    float2* covP = (float2*)(wsum + 256);
    float4* clP  = (float4*)((float*)covP + 65536);

    // d_out scratch (4 MB): fragment tables (2 MB) + Cm (2 MB).
    // head overwrites all of d_out at the end; deterministic per launch.
    short* WhT_blk = (short*)d_out;
    short* WlT_blk = WhT_blk + 262144;
    short* WhT_lin = WlT_blk + 262144;
    short* WlT_lin = WhT_lin + 262144;
    float* Cm      = (float*)(WlT_lin + 262144);         // [2048,256]

    wsum_kernel<<<64, 256, 0, stream>>>(W, wsum);
    prep_kernel<<<dim3(8, 8), 256, 0, stream>>>(cov, ldng, covP, clP);
    gemm_kernel<<<dim3(128, 4), 256, 0, stream>>>(x, W, C);

    prep_w_blk<<<128, 256, 0, stream>>>(W, WhT_blk, WlT_blk);
    prep_w_lin<<<128, 256, 0, stream>>>(W, WhT_lin, WlT_lin);

    // V0: R11 exact (negative control)
    mfma_gemm<0, 0><<<64, 512, 0, stream>>>(x, WhT_blk, WlT_blk, Cm);
    verify0<<<512, 256, 0, stream>>>(C, Cm);
    // V1: D-write transposed
    mfma_gemm<0, 1><<<64, 512, 0, stream>>>(x, WhT_blk, WlT_blk, Cm);
    verify1<<<512, 256, 0, stream>>>(C, Cm);
    // V2: A linear, B blocked
    mfma_gemm<1, 0><<<64, 512, 0, stream>>>(x, WhT_blk, WlT_blk, Cm);
    verify2<<<512, 256, 0, stream>>>(C, Cm);
    // V3: A blocked, B linear
    mfma_gemm<0, 0><<<64, 512, 0, stream>>>(x, WhT_lin, WlT_lin, Cm);
    verify3<<<512, 256, 0, stream>>>(C, Cm);

    head_kernel<<<1024, 256, 0, stream>>>(C, wsum, covP, clP, cov, ldng, out);
}

// Round 16
// 179.970 us; speedup vs baseline: 3.0572x; 3.0572x over previous
//
#include <hip/hip_runtime.h>

#define L2E 1.4426950408889634f

typedef short bf16x8 __attribute__((ext_vector_type(8)));
typedef short short4v __attribute__((ext_vector_type(4)));
typedef float f32x4 __attribute__((ext_vector_type(4)));

__device__ __forceinline__ short bf16hi(float x) {
    return (short)(__builtin_bit_cast(unsigned int, x) >> 16);
}
__device__ __forceinline__ float bf16tof(short h) {
    return __builtin_bit_cast(float, ((unsigned int)(unsigned short)h) << 16);
}

// ---------------- Wsum ----------------
__global__ __launch_bounds__(256) void wsum_kernel(const float* __restrict__ W,
                                                   float* __restrict__ wsum) {
    int wave = threadIdx.x >> 6, lane = threadIdx.x & 63;
    int h = blockIdx.x * 4 + wave;
    const float* row = W + (size_t)h * 1024;
    float s = 0.f;
#pragma unroll
    for (int i = 0; i < 16; ++i) s += row[lane + 64 * i];
#pragma unroll
    for (int off = 32; off; off >>= 1) s += __shfl_xor(s, off, 64);
    if (lane == 0) wsum[h] = s;
}

// ------- prep: pair-major zero-diag transposed tables (R13, proven) ---------
__global__ __launch_bounds__(256) void prep_kernel(const float* __restrict__ cov,
                                                   const float* __restrict__ ld,
                                                   float2* __restrict__ covP,
                                                   float4* __restrict__ clP) {
    __shared__ float tc[32][33];
    __shared__ float tl[32][33];
    const int bx = blockIdx.x * 32, by = blockIdx.y * 32;
    const int x = threadIdx.x & 31;
    const int y = threadIdx.x >> 5;
#pragma unroll
    for (int i = 0; i < 32; i += 8) {
        int r = by + y + i, c = bx + x;
        float cv = cov[(size_t)r * 256 + c];
        float lv = ld[(size_t)r * 256 + c];
        if (r == c) { cv = 0.f; lv = 0.f; }
        tc[y + i][x] = cv; tl[y + i][x] = lv;
    }
    __syncthreads();
    const int k = by + x;
#pragma unroll
    for (int i2 = 0; i2 < 16; i2 += 8) {
        int y2 = y + i2;
        int jp = (bx >> 1) + y2;
        float c0 = tc[x][2 * y2],     l0 = tl[x][2 * y2];
        float c1 = tc[x][2 * y2 + 1], l1 = tl[x][2 * y2 + 1];
        covP[(size_t)jp * 256 + k] = make_float2(c0, c1);
        clP[(size_t)jp * 256 + k]  = make_float4(c0, l0, c1, l1);
    }
}

// ------- probe: empirically discover MFMA slot pairing + D map --------------
// My staging convention ("my-k"): slot (lane l, elem i) <-> q = 16*(i>>2) +
// 4*(l>>4) + (i&3); matrix-dim = l&15. Probe 1: A slot q holds q+1, B is an
// indicator at my-slot j  =>  D == sigma(j)+1 everywhere (sigma = composite
// A/B pairing twist). Probe 2: A[r][q] = 16r+q, B = sigma-corrected identity
// =>  acc[reg] = 16*Crow + Ccol for this (lane,reg)  ==  dmap.
__global__ __launch_bounds__(64) void probe_kernel(int* __restrict__ sigma,
                                                   int* __restrict__ dmap) {
    const int l = threadIdx.x;
    __shared__ int sig[32];
    int q[8];
#pragma unroll
    for (int i = 0; i < 8; ++i) q[i] = 16 * (i >> 2) + 4 * (l >> 4) + (i & 3);

    for (int j = 0; j < 32; ++j) {
        short a[8], b[8];
#pragma unroll
        for (int i = 0; i < 8; ++i) {
            a[i] = bf16hi((float)(q[i] + 1));
            b[i] = (q[i] == j) ? bf16hi(1.0f) : (short)0;
        }
        f32x4 acc = {};
        acc = __builtin_amdgcn_mfma_f32_16x16x32_bf16(*(bf16x8*)a, *(bf16x8*)b, acc, 0, 0, 0);
        if (l == 0) sig[j] = (((int)(acc[0] + 0.5f)) - 1) & 31;
    }
    __syncthreads();
    if (l < 32) sigma[l] = sig[l];

    short a2[8], b2[8];
#pragma unroll
    for (int i = 0; i < 8; ++i) {
        a2[i] = bf16hi((float)(q[i] < 16 ? 16 * (l & 15) + q[i] : 0));
        b2[i] = ((l & 15) == sig[q[i]]) ? bf16hi(1.0f) : (short)0;
    }
    f32x4 acc2 = {};
    acc2 = __builtin_amdgcn_mfma_f32_16x16x32_bf16(*(bf16x8*)a2, *(bf16x8*)b2, acc2, 0, 0, 0);
#pragma unroll
    for (int r = 0; r < 4; ++r)
        dmap[l * 4 + r] = ((int)(acc2[r] + 0.5f)) & 255;
}

// ------- prep_w: W -> hi/lo bf16 fragment tables, sigma-corrected -----------
__global__ __launch_bounds__(256) void prep_w_kernel(const float* __restrict__ W,
                                                     const int* __restrict__ sigma,
                                                     short* __restrict__ WhT,
                                                     short* __restrict__ WlT) {
    __shared__ int sig[32];
    if (threadIdx.x < 32) sig[threadIdx.x] = sigma[threadIdx.x];
    __syncthreads();
    int id = blockIdx.x * 256 + threadIdx.x;
    int rem = id & 1023;
    int s = id >> 10, c = rem >> 6, l = rem & 63;
    int n = 16 * c + (l & 15);
    const float* p = W + (size_t)n * 1024 + 32 * s;
    short h[8], lo[8];
#pragma unroll
    for (int i = 0; i < 8; ++i) {
        int q = 16 * (i >> 2) + 4 * (l >> 4) + (i & 3);
        float v = p[sig[q]];
        short hh = bf16hi(v);
        h[i] = hh; lo[i] = bf16hi(v - bf16tof(hh));
    }
    *(bf16x8*)(WhT + (size_t)id * 8) = *(bf16x8*)h;
    *(bf16x8*)(WlT + (size_t)id * 8) = *(bf16x8*)lo;
}

// ---------------- GEMM fp32 (R5, proven) -> Cref ----------------------------
#define BK 16
#define LDT 68

__global__ __launch_bounds__(256) void gemm_kernel(const float* __restrict__ X,
                                                   const float* __restrict__ W,
                                                   float* __restrict__ C) {
    __shared__ float As[BK][LDT];
    __shared__ float Bs[BK][LDT];
    const int tid = threadIdx.x;
    const int row = tid >> 2;
    const int c4  = (tid & 3) << 2;
    const int gm0 = blockIdx.x * 64;
    const int gn0 = blockIdx.y * 64;
    const int tx = tid & 15, ty = tid >> 4;
    float acc[4][4] = {};
    const float* Xp = X + (size_t)(gm0 + row) * 1024 + c4;
    const float* Wp = W + (size_t)(gn0 + row) * 1024 + c4;

    float4 a = *(const float4*)(Xp);
    float4 b = *(const float4*)(Wp);
    for (int kt = 0; kt < 1024; kt += BK) {
        __syncthreads();
        As[c4 + 0][row] = a.x; As[c4 + 1][row] = a.y;
        As[c4 + 2][row] = a.z; As[c4 + 3][row] = a.w;
        Bs[c4 + 0][row] = b.x; Bs[c4 + 1][row] = b.y;
        Bs[c4 + 2][row] = b.z; Bs[c4 + 3][row] = b.w;
        __syncthreads();
        if (kt + BK < 1024) {
            a = *(const float4*)(Xp + kt + BK);
            b = *(const float4*)(Wp + kt + BK);
        }
#pragma unroll
        for (int kk = 0; kk < BK; ++kk) {
            float4 av = *(const float4*)&As[kk][ty << 2];
            float4 bv = *(const float4*)&Bs[kk][tx << 2];
            float am[4] = {av.x, av.y, av.z, av.w};
            float bn[4] = {bv.x, bv.y, bv.z, bv.w};
#pragma unroll
            for (int i = 0; i < 4; ++i)
#pragma unroll
                for (int j = 0; j < 4; ++j)
                    acc[i][j] = __builtin_fmaf(am[i], bn[j], acc[i][j]);
        }
    }
#pragma unroll
    for (int i = 0; i < 4; ++i) {
        float4 o = {acc[i][0], acc[i][1], acc[i][2], acc[i][3]};
        *(float4*)(C + (size_t)(gm0 + (ty << 2) + i) * 256 + gn0 + (tx << 2)) = o;
    }
}

// ---------------- MFMA GEMM (calibrated), rows [0,2048) -> Cm ---------------
__global__ __launch_bounds__(512) void mfma_gemm(const float* __restrict__ X,
                                                 const short* __restrict__ WhT,
                                                 const short* __restrict__ WlT,
                                                 const int* __restrict__ dmap,
                                                 float* __restrict__ Cm) {
    __shared__ short Ah[2][64][8];
    __shared__ short Al[2][64][8];
    __shared__ short Wh[16][64][8];
    __shared__ short Wl[16][64][8];
    const int tid = threadIdx.x;
    const int l = tid & 63, w = tid >> 6;
    const int gm0 = blockIdx.x * 32;

    const int xr = tid >> 3, xg = tid & 7;
    const float* Xp = X + (size_t)(gm0 + xr) * 1024 + 4 * xg;

    float4 xv;
    bf16x8 wh0, wh1, wl0, wl1;
    if (tid < 256) xv = *(const float4*)(Xp);
    wh0 = *(const bf16x8*)(WhT + (size_t)tid * 8);
    wh1 = *(const bf16x8*)(WhT + (size_t)(tid + 512) * 8);
    wl0 = *(const bf16x8*)(WlT + (size_t)tid * 8);
    wl1 = *(const bf16x8*)(WlT + (size_t)(tid + 512) * 8);

    const int rt = w & 1, cg = w >> 1;
    f32x4 acc[4] = {};

    for (int s = 0; s < 32; ++s) {
        __syncthreads();
        if (tid < 256) {
            float vv[4] = {xv.x, xv.y, xv.z, xv.w};
            short h[4], lo[4];
#pragma unroll
            for (int i = 0; i < 4; ++i) {
                short hh = bf16hi(vv[i]);
                h[i] = hh; lo[i] = bf16hi(vv[i] - bf16tof(hh));
            }
            int lane = (xr & 15) + 16 * (xg & 3);
            int e0 = (xg >> 2) * 4;
            *(short4v*)&Ah[xr >> 4][lane][e0] = *(short4v*)h;
            *(short4v*)&Al[xr >> 4][lane][e0] = *(short4v*)lo;
        }
        ((bf16x8*)Wh)[tid]       = wh0;
        ((bf16x8*)Wh)[tid + 512] = wh1;
        ((bf16x8*)Wl)[tid]       = wl0;
        ((bf16x8*)Wl)[tid + 512] = wl1;
        __syncthreads();
        if (s < 31) {
            if (tid < 256) xv = *(const float4*)(Xp + (s + 1) * 32);
            const size_t wo = (size_t)(s + 1) * 8192;
            wh0 = *(const bf16x8*)(WhT + wo + (size_t)tid * 8);
            wh1 = *(const bf16x8*)(WhT + wo + (size_t)(tid + 512) * 8);
            wl0 = *(const bf16x8*)(WlT + wo + (size_t)tid * 8);
            wl1 = *(const bf16x8*)(WlT + wo + (size_t)(tid + 512) * 8);
        }
        bf16x8 ah = *(bf16x8*)&Ah[rt][l][0];
        bf16x8 al = *(bf16x8*)&Al[rt][l][0];
#pragma unroll
        for (int cc = 0; cc < 4; ++cc) {
            int c = cg * 4 + cc;
            bf16x8 bh = *(bf16x8*)&Wh[c][l][0];
            bf16x8 bl = *(bf16x8*)&Wl[c][l][0];
            acc[cc] = __builtin_amdgcn_mfma_f32_16x16x32_bf16(ah, bh, acc[cc], 0, 0, 0);
            acc[cc] = __builtin_amdgcn_mfma_f32_16x16x32_bf16(ah, bl, acc[cc], 0, 0, 0);
            acc[cc] = __builtin_amdgcn_mfma_f32_16x16x32_bf16(al, bh, acc[cc], 0, 0, 0);
        }
    }
    // D-write via measured dmap: v = 16*row + col for this (lane, reg)
    const int4 dm = *(const int4*)(dmap + 4 * l);
    const int vr[4] = {dm.x, dm.y, dm.z, dm.w};
#pragma unroll
    for (int cc = 0; cc < 4; ++cc) {
        int c = cg * 4 + cc;
#pragma unroll
        for (int r = 0; r < 4; ++r) {
            int v = vr[r];
            Cm[(size_t)(gm0 + rt * 16 + (v >> 4)) * 256 + c * 16 + (v & 15)] = acc[cc][r];
        }
    }
}

// ------- verify: spin ~70us iff mismatch (marker in rocprof) ----------------
__global__ __launch_bounds__(256) void verify_mfma(const float* __restrict__ Cref,
                                                   const float* __restrict__ Cm) {
    int idx = (blockIdx.x * 256 + threadIdx.x) * 4;
    float4 a = *(const float4*)(Cref + idx);
    float4 b = *(const float4*)(Cm + idx);
    bool bad = fabsf(a.x - b.x) > 0.25f || fabsf(a.y - b.y) > 0.25f ||
               fabsf(a.z - b.z) > 0.25f || fabsf(a.w - b.w) > 0.25f;
    if (__any(bad)) {
        float x = (float)threadIdx.x;
        for (int i = 0; i < 30000; ++i) x = __builtin_fmaf(x, 1.0000001f, 1e-9f);
        asm volatile("" :: "v"(x));
    }
}

// ---------------- Head (R13, proven) ----------------------------------------
#define NB 4

__global__ __launch_bounds__(256) void head_kernel(const float* __restrict__ C,
                                                   const float* __restrict__ wsum,
                                                   const float2* __restrict__ covP,
                                                   const float4* __restrict__ clP,
                                                   const float* __restrict__ cov,
                                                   const float* __restrict__ ld,
                                                   float* __restrict__ out) {
    __shared__ float4 omI[256];
    __shared__ float4 vaI[256];
    const int k = threadIdx.x;
    const int b0 = blockIdx.x * NB;

    const float ws = wsum[k];
    const float cdiag = cov[(size_t)k * 257];
    const float ldiag = ld[(size_t)k * 257];

    float mk[NB], vak[NB], omk[NB], sp[NB], pmax[NB], pmin[NB];
#pragma unroll
    for (int b = 0; b < NB; ++b) {
        float va = C[(size_t)(2 * (b0 + b)) * 256 + k];
        float ms = C[(size_t)(2 * (b0 + b) + 1) * 256 + k];
        float o  = ws - ms;
        mk[b] = ms; vak[b] = va; omk[b] = o;
        ((float*)&omI[k])[b] = o;
        ((float*)&vaI[k])[b] = va;
        sp[b] = 0.f; pmax[b] = 0.f; pmin[b] = 0.f;
    }
    __syncthreads();

    const float2* cp = covP + k;
#pragma unroll 4
    for (int jp = 0; jp < 128; ++jp) {
        float2 cv = cp[(size_t)jp * 256];
        float4 om0 = omI[2 * jp];
        float4 om1 = omI[2 * jp + 1];
        float o0[4] = {om0.x, om0.y, om0.z, om0.w};
        float o1[4] = {om1.x, om1.y, om1.z, om1.w};
#pragma unroll
        for (int b = 0; b < NB; ++b) {
            float p0 = cv.x * o0[b];
            float p1 = cv.y * o1[b];
            sp[b]  += p0 + p1;
            pmax[b] = fmaxf(fmaxf(pmax[b], p0), p1);
            pmin[b] = fminf(fminf(pmin[b], p0), p1);
        }
    }

    float c1[NB], c0[NB], ek[NB], se[NB], dp[NB];
#pragma unroll
    for (int b = 0; b < NB; ++b) {
        float m   = mk[b];
        float pkk = cdiag * omk[b];
        float rkk = __builtin_fmaf(m, pkk, 1.0f);
        float sum = __builtin_fmaf(m, sp[b] + pkk, 1.0f);
        float iv  = __builtin_amdgcn_rcpf(sum);
        float rmax = (m >= 0.f) ? m * pmax[b] : m * pmin[b];
        float rmin = (m >= 0.f) ? m * pmin[b] : m * pmax[b];
        rmax = fmaxf(rmax, rkk);
        rmin = fminf(rmin, rkk);
        float mx = (iv >= 0.f) ? iv * rmax : iv * rmin;
        c1[b] = m * iv * L2E;
        c0[b] = -mx * L2E;
        ek[b] = __builtin_amdgcn_exp2f(__builtin_fmaf(rkk * iv, L2E, c0[b]));
        se[b] = 0.f; dp[b] = 0.f;
    }

    const float4* lp = clP + k;
#pragma unroll 4
    for (int jp = 0; jp < 128; ++jp) {
        float4 cl = lp[(size_t)jp * 256];
        float4 om0 = omI[2 * jp];
        float4 om1 = omI[2 * jp + 1];
        float4 va0 = vaI[2 * jp];
        float4 va1 = vaI[2 * jp + 1];
        float o0[4] = {om0.x, om0.y, om0.z, om0.w};
        float o1[4] = {om1.x, om1.y, om1.z, om1.w};
        float v0[4] = {va0.x, va0.y, va0.z, va0.w};
        float v1[4] = {va1.x, va1.y, va1.z, va1.w};
#pragma unroll
        for (int b = 0; b < NB; ++b) {
            float p0 = cl.x * o0[b];
            float e0 = __builtin_amdgcn_exp2f(__builtin_fmaf(p0, c1[b], c0[b]));
            float p1 = cl.z * o1[b];
            float e1 = __builtin_amdgcn_exp2f(__builtin_fmaf(p1, c1[b], c0[b]));
            se[b] += e0 + e1;
            dp[b]  = __builtin_fmaf(e0, cl.y * v0[b], dp[b]);
            dp[b]  = __builtin_fmaf(e1, cl.w * v1[b], dp[b]);
        }
    }

#pragma unroll
    for (int b = 0; b < NB; ++b) {
        float espur = __builtin_amdgcn_exp2f(c0[b]);
        float sef = se[b] + (ek[b] - espur);
        float dpf = __builtin_fmaf(ek[b], ldiag * vak[b], dp[b]);
        out[(size_t)(b0 + b) * 256 + k] = dpf * __builtin_amdgcn_rcpf(sef);
    }
}

extern "C" void kernel_launch(void* const* d_in, const int* in_sizes, int n_in,
                              void* d_out, int out_size, void* d_ws, size_t ws_size,
                              hipStream_t stream) {
    const float* x    = (const float*)d_in[0];   // [4096,2,1024]
    const float* W    = (const float*)d_in[1];   // [256,1024]
    const float* cov  = (const float*)d_in[2];   // [256,256]
    const float* ldng = (const float*)d_in[3];   // [256,256]
    float* out = (float*)d_out;                  // [4096,256]

    // d_ws
    float*  Cref = (float*)d_ws;                         // [8192,256]
    float*  wsum = Cref + (size_t)8192 * 256;            // [256]
    float2* covP = (float2*)(wsum + 256);                // [128*256]
    float4* clP  = (float4*)((float*)covP + 65536);      // [128*256]
    int*    sigma = (int*)((float*)clP + 262144);        // [32]
    int*    dmap  = sigma + 32;                          // [256]

    // d_out scratch: tables (1MB) + Cm (2MB); head overwrites d_out at the end
    short* WhT = (short*)d_out;                          // [32768*8]
    short* WlT = WhT + (size_t)262144;                   // [32768*8]
    float* Cm  = (float*)(WlT + 262144);                 // [2048,256]

    wsum_kernel<<<64, 256, 0, stream>>>(W, wsum);
    prep_kernel<<<dim3(8, 8), 256, 0, stream>>>(cov, ldng, covP, clP);
    probe_kernel<<<1, 64, 0, stream>>>(sigma, dmap);
    prep_w_kernel<<<128, 256, 0, stream>>>(W, sigma, WhT, WlT);
    gemm_kernel<<<dim3(128, 4), 256, 0, stream>>>(x, W, Cref);
    mfma_gemm<<<64, 512, 0, stream>>>(x, WhT, WlT, dmap, Cm);
    verify_mfma<<<512, 256, 0, stream>>>(Cref, Cm);
    head_kernel<<<1024, 256, 0, stream>>>(Cref, wsum, covP, clP, cov, ldng, out);
}

// Round 18
// 147.402 us; speedup vs baseline: 3.7327x; 1.2209x over previous
//
#include <hip/hip_runtime.h>

#define L2E 1.4426950408889634f

// ---------------- Wsum: wsum[h] = sum_n W[h][n] ----------------
__global__ __launch_bounds__(256) void wsum_kernel(const float* __restrict__ W,
                                                   float* __restrict__ wsum) {
    int wave = threadIdx.x >> 6, lane = threadIdx.x & 63;
    int h = blockIdx.x * 4 + wave;
    const float* row = W + (size_t)h * 1024;
    float s = 0.f;
#pragma unroll
    for (int i = 0; i < 16; ++i) s += row[lane + 64 * i];
#pragma unroll
    for (int off = 32; off; off >>= 1) s += __shfl_xor(s, off, 64);
    if (lane == 0) wsum[h] = s;
}

// ------- prep: pair-major zero-diag transposed tables (R13, proven) ---------
__global__ __launch_bounds__(256) void prep_kernel(const float* __restrict__ cov,
                                                   const float* __restrict__ ld,
                                                   float2* __restrict__ covP,
                                                   float4* __restrict__ clP) {
    __shared__ float tc[32][33];
    __shared__ float tl[32][33];
    const int bx = blockIdx.x * 32, by = blockIdx.y * 32;
    const int x = threadIdx.x & 31;
    const int y = threadIdx.x >> 5;
#pragma unroll
    for (int i = 0; i < 32; i += 8) {
        int r = by + y + i, c = bx + x;
        float cv = cov[(size_t)r * 256 + c];
        float lv = ld[(size_t)r * 256 + c];
        if (r == c) { cv = 0.f; lv = 0.f; }
        tc[y + i][x] = cv; tl[y + i][x] = lv;
    }
    __syncthreads();
    const int k = by + x;
#pragma unroll
    for (int i2 = 0; i2 < 16; i2 += 8) {
        int y2 = y + i2;
        int jp = (bx >> 1) + y2;
        float c0 = tc[x][2 * y2],     l0 = tl[x][2 * y2];
        float c1 = tc[x][2 * y2 + 1], l1 = tl[x][2 * y2 + 1];
        covP[(size_t)jp * 256 + k] = make_float2(c0, c1);
        clP[(size_t)jp * 256 + k]  = make_float4(c0, l0, c1, l1);
    }
}

// ---------------- GEMM fp32 (R5, proven): C[8192,256] = X @ W^T -------------
#define BK 16
#define LDT 68

__global__ __launch_bounds__(256) void gemm_kernel(const float* __restrict__ X,
                                                   const float* __restrict__ W,
                                                   float* __restrict__ C) {
    __shared__ float As[BK][LDT];
    __shared__ float Bs[BK][LDT];
    const int tid = threadIdx.x;
    const int row = tid >> 2;
    const int c4  = (tid & 3) << 2;
    const int gm0 = blockIdx.x * 64;
    const int gn0 = blockIdx.y * 64;
    const int tx = tid & 15, ty = tid >> 4;
    float acc[4][4] = {};
    const float* Xp = X + (size_t)(gm0 + row) * 1024 + c4;
    const float* Wp = W + (size_t)(gn0 + row) * 1024 + c4;

    float4 a = *(const float4*)(Xp);
    float4 b = *(const float4*)(Wp);
    for (int kt = 0; kt < 1024; kt += BK) {
        __syncthreads();
        As[c4 + 0][row] = a.x; As[c4 + 1][row] = a.y;
        As[c4 + 2][row] = a.z; As[c4 + 3][row] = a.w;
        Bs[c4 + 0][row] = b.x; Bs[c4 + 1][row] = b.y;
        Bs[c4 + 2][row] = b.z; Bs[c4 + 3][row] = b.w;
        __syncthreads();
        if (kt + BK < 1024) {
            a = *(const float4*)(Xp + kt + BK);
            b = *(const float4*)(Wp + kt + BK);
        }
#pragma unroll
        for (int kk = 0; kk < BK; ++kk) {
            float4 av = *(const float4*)&As[kk][ty << 2];
            float4 bv = *(const float4*)&Bs[kk][tx << 2];
            float am[4] = {av.x, av.y, av.z, av.w};
            float bn[4] = {bv.x, bv.y, bv.z, bv.w};
#pragma unroll
            for (int i = 0; i < 4; ++i)
#pragma unroll
                for (int j = 0; j < 4; ++j)
                    acc[i][j] = __builtin_fmaf(am[i], bn[j], acc[i][j]);
        }
    }
#pragma unroll
    for (int i = 0; i < 4; ++i) {
        float4 o = {acc[i][0], acc[i][1], acc[i][2], acc[i][3]};
        *(float4*)(C + (size_t)(gm0 + (ty << 2) + i) * 256 + gn0 + (tx << 2)) = o;
    }
}

// ---------------- Head: j-split, 512 threads (half h owns jp in [64h,64h+64))
// Same per-element math as R13 (proven); partial sums combined via LDS.
#define NB 4

__global__ __launch_bounds__(512) void head_kernel(const float* __restrict__ C,
                                                   const float* __restrict__ wsum,
                                                   const float2* __restrict__ covP,
                                                   const float4* __restrict__ clP,
                                                   const float* __restrict__ cov,
                                                   const float* __restrict__ ld,
                                                   float* __restrict__ out) {
    __shared__ float4 omI[256];
    __shared__ float4 vaI[256];
    __shared__ float red[2][NB][3][256];     // 24KB; pass2 reuses slots 0,1
    const int t = threadIdx.x;
    const int k = t & 255;
    const int h = t >> 8;
    const int b0 = blockIdx.x * NB;

    const float ws = wsum[k];
    const float cdiag = cov[(size_t)k * 257];
    const float ldiag = ld[(size_t)k * 257];

    float mk[NB], vak[NB], omk[NB];
    if (h == 0) {
#pragma unroll
        for (int b = 0; b < NB; ++b) {
            float va = C[(size_t)(2 * (b0 + b)) * 256 + k];
            float ms = C[(size_t)(2 * (b0 + b) + 1) * 256 + k];
            float o  = ws - ms;
            mk[b] = ms; vak[b] = va; omk[b] = o;
            ((float*)&omI[k])[b] = o;
            ((float*)&vaI[k])[b] = va;
        }
    }
    __syncthreads();
    if (h == 1) {
#pragma unroll
        for (int b = 0; b < NB; ++b) {
            float o  = ((float*)&omI[k])[b];
            float va = ((float*)&vaI[k])[b];
            omk[b] = o; vak[b] = va; mk[b] = ws - o;   // ms = ws - o
        }
    }

    float sp[NB], pmax[NB], pmin[NB];
#pragma unroll
    for (int b = 0; b < NB; ++b) { sp[b] = 0.f; pmax[b] = 0.f; pmin[b] = 0.f; }

    const float2* cp = covP + k;
    const int jp0 = h << 6;

    // ---- pass 1 (64 jp per half): off-diag row sum + exact extrema ----
#pragma unroll 4
    for (int jj = 0; jj < 64; ++jj) {
        int jp = jp0 + jj;
        float2 cv = cp[(size_t)jp * 256];
        float4 om0 = omI[2 * jp];
        float4 om1 = omI[2 * jp + 1];
        float o0[4] = {om0.x, om0.y, om0.z, om0.w};
        float o1[4] = {om1.x, om1.y, om1.z, om1.w};
#pragma unroll
        for (int b = 0; b < NB; ++b) {
            float p0 = cv.x * o0[b];
            float p1 = cv.y * o1[b];
            sp[b]  += p0 + p1;
            pmax[b] = fmaxf(fmaxf(pmax[b], p0), p1);
            pmin[b] = fminf(fminf(pmin[b], p0), p1);
        }
    }

#pragma unroll
    for (int b = 0; b < NB; ++b) {
        red[h][b][0][k] = sp[b];
        red[h][b][1][k] = pmax[b];
        red[h][b][2][k] = pmin[b];
    }
    __syncthreads();
    const int oh = h ^ 1;
#pragma unroll
    for (int b = 0; b < NB; ++b) {
        sp[b]  += red[oh][b][0][k];
        pmax[b] = fmaxf(pmax[b], red[oh][b][1][k]);
        pmin[b] = fminf(pmin[b], red[oh][b][2][k]);
    }
    __syncthreads();   // all combine-reads done before red is reused below

    // ---- per-b softmax constants (both halves compute identically) ----
    float c1[NB], c0[NB], ek[NB], se[NB], dp[NB];
#pragma unroll
    for (int b = 0; b < NB; ++b) {
        float m   = mk[b];
        float pkk = cdiag * omk[b];
        float rkk = __builtin_fmaf(m, pkk, 1.0f);
        float sum = __builtin_fmaf(m, sp[b] + pkk, 1.0f);
        float iv  = __builtin_amdgcn_rcpf(sum);
        float rmax = (m >= 0.f) ? m * pmax[b] : m * pmin[b];
        float rmin = (m >= 0.f) ? m * pmin[b] : m * pmax[b];
        rmax = fmaxf(rmax, rkk);
        rmin = fminf(rmin, rkk);
        float mx = (iv >= 0.f) ? iv * rmax : iv * rmin;   // == max_j w_j
        c1[b] = m * iv * L2E;
        c0[b] = -mx * L2E;
        ek[b] = __builtin_amdgcn_exp2f(__builtin_fmaf(rkk * iv, L2E, c0[b]));
        se[b] = 0.f; dp[b] = 0.f;
    }

    const float4* lp = clP + k;

    // ---- pass 2 (64 jp per half): exp + weighted dot ----
#pragma unroll 4
    for (int jj = 0; jj < 64; ++jj) {
        int jp = jp0 + jj;
        float4 cl = lp[(size_t)jp * 256];
        float4 om0 = omI[2 * jp];
        float4 om1 = omI[2 * jp + 1];
        float4 va0 = vaI[2 * jp];
        float4 va1 = vaI[2 * jp + 1];
        float o0[4] = {om0.x, om0.y, om0.z, om0.w};
        float o1[4] = {om1.x, om1.y, om1.z, om1.w};
        float v0[4] = {va0.x, va0.y, va0.z, va0.w};
        float v1[4] = {va1.x, va1.y, va1.z, va1.w};
#pragma unroll
        for (int b = 0; b < NB; ++b) {
            float p0 = cl.x * o0[b];
            float e0 = __builtin_amdgcn_exp2f(__builtin_fmaf(p0, c1[b], c0[b]));
            float p1 = cl.z * o1[b];
            float e1 = __builtin_amdgcn_exp2f(__builtin_fmaf(p1, c1[b], c0[b]));
            se[b] += e0 + e1;
            dp[b]  = __builtin_fmaf(e0, cl.y * v0[b], dp[b]);
            dp[b]  = __builtin_fmaf(e1, cl.w * v1[b], dp[b]);
        }
    }

#pragma unroll
    for (int b = 0; b < NB; ++b) {
        red[h][b][0][k] = se[b];
        red[h][b][1][k] = dp[b];
    }
    __syncthreads();

    // ---- finalize (half 0): combine halves, diag swap, write ----
    if (h == 0) {
#pragma unroll
        for (int b = 0; b < NB; ++b) {
            float sef = se[b] + red[1][b][0][k];
            float dpf = dp[b] + red[1][b][1][k];
            float espur = __builtin_amdgcn_exp2f(c0[b]);
            sef += ek[b] - espur;
            dpf  = __builtin_fmaf(ek[b], ldiag * vak[b], dpf);
            out[(size_t)(b0 + b) * 256 + k] = dpf * __builtin_amdgcn_rcpf(sef);
        }
    }
}

extern "C" void kernel_launch(void* const* d_in, const int* in_sizes, int n_in,
                              void* d_out, int out_size, void* d_ws, size_t ws_size,
                              hipStream_t stream) {
    const float* x    = (const float*)d_in[0];   // [4096,2,1024]
    const float* W    = (const float*)d_in[1];   // [256,1024]
    const float* cov  = (const float*)d_in[2];   // [256,256]
    const float* ldng = (const float*)d_in[3];   // [256,256]
    float* out = (float*)d_out;                  // [4096,256]

    // ws: R13-proven footprint (8.83 MB)
    float*  C    = (float*)d_ws;                         // [8192,256]
    float*  wsum = C + (size_t)8192 * 256;               // [256]
    float2* covP = (float2*)(wsum + 256);                // [128*256] pairs
    float4* clP  = (float4*)((float*)covP + 65536);      // [128*256] quads

    wsum_kernel<<<64, 256, 0, stream>>>(W, wsum);
    prep_kernel<<<dim3(8, 8), 256, 0, stream>>>(cov, ldng, covP, clP);
    gemm_kernel<<<dim3(128, 4), 256, 0, stream>>>(x, W, C);
    head_kernel<<<1024, 512, 0, stream>>>(C, wsum, covP, clP, cov, ldng, out);
}